// Round 8
// baseline (168.658 us; speedup 1.0000x reference)
//
#include <hip/hip_runtime.h>

#define CIN 512
#define COUT 512
#define HH 64
#define WW 64
#define BB 8
#define KTOT 4608   // 512*9

#define XPD 66                // padded spatial dim: index = coord+1, coord in -1..64
#define BUFSH (3 * 66 * 64)   // 12672 shorts per LDS buffer (3 rows x 66 slices x 64 ch)
#define ROWB (66 * 128)       // 8448 bytes per LDS input row

typedef __attribute__((ext_vector_type(8))) short short8;
typedef __attribute__((ext_vector_type(4))) float f32x4;

__device__ inline unsigned short f2bf(float f) {
    unsigned int u = __float_as_uint(f);
    u += 0x7FFFu + ((u >> 16) & 1u);   // round-to-nearest-even
    return (unsigned short)(u >> 16);
}

__device__ inline void gll16(const void* g, void* l) {
    __builtin_amdgcn_global_load_lds(
        (const __attribute__((address_space(1))) unsigned int*)g,
        (__attribute__((address_space(3))) unsigned int*)l, 16, 0, 0);
}

// ---------------- Phase -1: zero the halo ring of XTP ----------------
__global__ __launch_bounds__(256) void zring_kernel(unsigned short* __restrict__ xtp) {
    const int e = blockIdx.x * 256 + threadIdx.x;   // 520*256 >= 8*260*64
    if (e >= BB * 260 * 64) return;
    const int unit = e & 63;
    const int sa = e >> 6;           // 0..2079
    const int b = sa / 260;
    const int s = sa - b * 260;
    int yy, xx;
    if (s < 66)       { yy = 0;        xx = s; }
    else if (s < 132) { yy = 65;       xx = s - 66; }
    else if (s < 196) { yy = s - 131;  xx = 0; }     // rows 1..64
    else              { yy = s - 195;  xx = 65; }    // rows 1..64
    *(short8*)(xtp + ((size_t)(b * XPD + yy) * XPD + xx) * 512 + unit * 8) =
        (short8){0, 0, 0, 0, 0, 0, 0, 0};
}

// ------- Phase 0: x [b][i][y][x] fp32 * (1+style[b][i]) -> XTP [b][y+1][x+1][i] bf16 -------
__global__ __launch_bounds__(256) void xpose_kernel(const float* __restrict__ x,
                                                    const float* __restrict__ style,
                                                    unsigned short* __restrict__ xtp) {
    __shared__ float tile[32 * 65];
    __shared__ float sst[32];
    const int ic = blockIdx.x;   // 16 groups of 32 channels
    const int y  = blockIdx.y;
    const int b  = blockIdx.z;
    const int t  = threadIdx.x;
    if (t < 32) sst[t] = style[b * CIN + ic * 32 + t] + 1.0f;
#pragma unroll
    for (int it = 0; it < 8; ++it) {
        int e = it * 256 + t;
        int ii = e >> 6, xx = e & 63;
        tile[ii * 65 + xx] = x[(((size_t)(b * CIN + ic * 32 + ii) * HH + y) << 6) + xx];
    }
    __syncthreads();
#pragma unroll
    for (int it = 0; it < 8; ++it) {
        int g = it * 256 + t;
        int xx = g >> 5, ii = g & 31;
        xtp[((size_t)(b * XPD + y + 1) * XPD + xx + 1) * 512 + ic * 32 + ii] =
            f2bf(tile[ii * 65 + xx] * sst[ii]);
    }
}

// ---------------- Phase 1a: pack w*c into MFMA fragment layout (batch-independent) -------
// Wpk flat: (((c*9 + tap)*32 + g)*64 + lane)*8 + e ; lane = l4*16+l15 holds
//   W[o = g*16+l15][i = c*32 + l4*8 + e],  c = 16 chunks of 32 input ch.
__global__ __launch_bounds__(256) void wpack_kernel(const float* __restrict__ weight,
                                                    unsigned short* __restrict__ wpk) {
    __shared__ float q[KTOT];
    const int o = blockIdx.x;
    const int t = threadIdx.x;
    const float* wrow = weight + (size_t)o * KTOT;   // e = i*9+tap
    const float cst = 1.0f / sqrtf((float)KTOT);
#pragma unroll
    for (int it = 0; it < 18; ++it) {
        int e = it * 256 + t;
        q[e] = wrow[e] * cst;
    }
    __syncthreads();
    const int g = o >> 4, l15 = o & 15;
    for (int m = t; m < 576; m += 256) {   // m -> (c, tap, l4)
        int c   = m / 36;
        int rem = m - c * 36;
        int tap = rem >> 2;
        int l4  = rem & 3;
        short8 v;
#pragma unroll
        for (int e = 0; e < 8; ++e)
            v[e] = (short)f2bf(q[(c * 32 + l4 * 8 + e) * 9 + tap]);
        *(short8*)(wpk + ((((size_t)c * 9 + tap) * 32 + g) * 64 + l4 * 16 + l15) * 8) = v;
    }
}

// ---------------- Phase 1b: sigma_inv[b][o] = rsqrt(c^2 * sum_i wsq[o,i]*(1+s)^2 + eps) ----
__global__ __launch_bounds__(256) void sigma_kernel(const float* __restrict__ weight,
                                                    const float* __restrict__ style,
                                                    float* __restrict__ siginv) {
    __shared__ float sred[4][8];
    const int o = blockIdx.x;
    const int t = threadIdx.x;
    const float* wrow = weight + (size_t)o * KTOT;
    float acc[8] = {0.f, 0.f, 0.f, 0.f, 0.f, 0.f, 0.f, 0.f};
#pragma unroll
    for (int ii = 0; ii < 2; ++ii) {
        const int i = t * 2 + ii;
        float wsq = 0.f;
#pragma unroll
        for (int tap = 0; tap < 9; ++tap) {
            float v = wrow[i * 9 + tap];
            wsq += v * v;
        }
#pragma unroll
        for (int b = 0; b < 8; ++b) {
            float s = style[b * CIN + i] + 1.0f;
            acc[b] += wsq * s * s;
        }
    }
#pragma unroll
    for (int b = 0; b < 8; ++b) {
        float v = acc[b];
#pragma unroll
        for (int off = 32; off > 0; off >>= 1) v += __shfl_down(v, off, 64);
        if ((t & 63) == 0) sred[t >> 6][b] = v;
    }
    __syncthreads();
    if (t < 8) {
        const float S = sred[0][t] + sred[1][t] + sred[2][t] + sred[3][t];
        siginv[t * COUT + o] = rsqrtf(S * (1.0f / (float)KTOT) + 1e-8f);
    }
}

// ---------------- Phase 2: implicit-GEMM conv ----------------
// block: 256 thr = 4 waves; tile 256 o x 1 output row x 64 px.
// wave og = wid: 64 o x 64 px -> acc[4][4] (64 AGPR). 3 blocks/CU (LDS 50.7 KB,
// launch_bounds(256,3) -> <=170 regs, 3 waves/SIMD).
// A-path: 2-deep static prefetch rotation af[3][4]; global phase G = ic*18+s is
// LINEAR in wpk byte offset (G*32768) -> seamless prefetch across ic boundaries.
// X: 3 input rows x 66 slices x 64 ch per buffer, XOR-8 swizzle (conflict-free).
__global__ __launch_bounds__(256, 3) void conv_kernel(const unsigned short* __restrict__ wpk,
                                                      const unsigned short* __restrict__ xtp,
                                                      const float* __restrict__ siginv,
                                                      const float* __restrict__ bias,
                                                      float* __restrict__ out) {
    __shared__ __align__(16) unsigned short xs[2 * BUFSH];   // 50688 B
    // XCD-aware decode: XCD k = bid&7 owns ob = k&1 (2.36 MB weight half, L2-hot)
    const int bid = blockIdx.x;
    const int k  = bid & 7;
    const int t  = bid >> 3;            // 0..127
    const int ob = k & 1;
    const int b  = (k >> 1) * 2 + (t >> 6);
    const int yb = t & 63;              // output row

    const int tid  = threadIdx.x;
    const int lane = tid & 63;
    const int wid_u = __builtin_amdgcn_readfirstlane(tid >> 6);   // wave-uniform -> SGPR
    const int l15 = lane & 15, l4 = lane >> 4;
    const int og = wid_u;               // 0..3, 64 o each
    const int g0 = ob * 16 + og * 4;    // o-frag base (frags of 16 o), scalar

    // ---- staging precompute: slices 0..197 (row = sl/66, col = sl%66), 128B each.
    // wave-load q covers slices q*8 + (lane>>3); unit = lane&7 phys, inverse-swizzled src.
    const int up = lane & 7;
    const unsigned short* srcq[6];
#pragma unroll
    for (int tq = 0; tq < 6; ++tq) {
        const int sl = (wid_u + tq * 4) * 8 + (lane >> 3);
        const int row = sl / 66, col = sl - row * 66;
        srcq[tq] = xtp + ((size_t)(b * XPD + yb + row) * XPD + col) * 512 +
                   (up ^ (col & 7)) * 8;
    }
    const int col6 = 60 + (lane >> 3);   // partial: slices 192..197 = row 2, col 60..65
    const unsigned short* src6 =
        xtp + ((size_t)(b * XPD + yb + 2) * XPD + col6) * 512 + (up ^ (col6 & 7)) * 8;

    // swizzled B ds byte-voffsets (col = l15+kx, phys unit = (ks*4+l4) ^ (col&7))
    int vB[3][2];
#pragma unroll
    for (int kx = 0; kx < 3; ++kx)
#pragma unroll
        for (int ks = 0; ks < 2; ++ks)
            vB[kx][ks] = (l15 + kx) * 128 + (((ks * 4 + l4) ^ ((l15 + kx) & 7)) * 16);

    f32x4 acc[4][4];
#pragma unroll
    for (int mi = 0; mi < 4; ++mi)
#pragma unroll
        for (int j = 0; j < 4; ++j) acc[mi][j] = (f32x4){0.f, 0.f, 0.f, 0.f};

    short8 af[3][4];   // 2-deep prefetch rotation, static indices only

    // A frag addr (shorts): aP + G*16384 + mi*512, G = ic*18 + s (s: ks = s/9, tap = s%9)
    const unsigned short* aP = wpk + (size_t)g0 * 512 + lane * 8;

#define STAGE(bufp, icq)                                                                  \
    do {                                                                                  \
        unsigned short* dbase = xs + (bufp) * BUFSH + wid_u * 512;                        \
        _Pragma("unroll") for (int tq = 0; tq < 6; ++tq)                                  \
            gll16(srcq[tq] + (size_t)(icq) * 64, dbase + tq * 2048);                      \
        if (wid_u == 0 && lane < 48)                                                      \
            gll16(src6 + (size_t)(icq) * 64, xs + (bufp) * BUFSH + 12288);                \
    } while (0)

#define PHASE(s, aPic, cbase)                                                             \
    do {                                                                                  \
        const unsigned short* pA = (aPic) + (size_t)((s) + 2) * 16384;                    \
        _Pragma("unroll") for (int mi = 0; mi < 4; ++mi)                                  \
            af[((s) + 2) % 3][mi] = *(const short8*)(pA + mi * 512);                      \
        short8 bfr[4];                                                                    \
        const char* bp = (const char*)xs + (cbase) +                                      \
                         (((s) % 9) / 3) * ROWB + vB[((s) % 9) % 3][(s) / 9];             \
        _Pragma("unroll") for (int j = 0; j < 4; ++j)                                     \
            bfr[j] = *(const short8*)(bp + j * 2048);                                     \
        __builtin_amdgcn_s_setprio(1);                                                    \
        _Pragma("unroll") for (int mi = 0; mi < 4; ++mi)                                  \
            _Pragma("unroll") for (int j = 0; j < 4; ++j)                                 \
                acc[mi][j] = __builtin_amdgcn_mfma_f32_16x16x32_bf16(                     \
                    af[(s) % 3][mi], bfr[j], acc[mi][j], 0, 0, 0);                        \
        __builtin_amdgcn_s_setprio(0);                                                    \
    } while (0)

    // prologue: prefetch A sets G=0,1 (ahead of staging in the vmcnt queue), then stage
    af[0][0] = *(const short8*)(aP + 0 * 512);
    af[0][1] = *(const short8*)(aP + 1 * 512);
    af[0][2] = *(const short8*)(aP + 2 * 512);
    af[0][3] = *(const short8*)(aP + 3 * 512);
    {
        const unsigned short* p1 = aP + 16384;
        af[1][0] = *(const short8*)(p1 + 0 * 512);
        af[1][1] = *(const short8*)(p1 + 1 * 512);
        af[1][2] = *(const short8*)(p1 + 2 * 512);
        af[1][3] = *(const short8*)(p1 + 3 * 512);
    }
    STAGE(0, 0);
    __syncthreads();

#pragma unroll 1
    for (int ic = 0; ic < 8; ++ic) {
        if (ic < 7) STAGE((ic + 1) & 1, ic + 1);
        const unsigned short* aPic = aP + (size_t)ic * (18 * 16384);
        const int cbase = (ic & 1) * (BUFSH * 2);   // bytes
#pragma unroll
        for (int s = 0; s < 18; ++s) {
            PHASE(s, aPic, cbase);   // s=16,17 prefetch next ic's sets 0,1 (linear G)
        }
        __syncthreads();
    }

    // epilogue: D-frag col = l15 (px), row = l4*4 + rr (o); scale by sigma_inv, add bias
#pragma unroll
    for (int mi = 0; mi < 4; ++mi) {
        const int obase = ob * 256 + og * 64 + mi * 16 + l4 * 4;
#pragma unroll
        for (int rr = 0; rr < 4; ++rr) {
            const int o = obase + rr;
            const float sv = siginv[b * COUT + o];
            const float bv = bias[o];
            float* orow = out + (((size_t)(b * COUT + o) * HH + yb) << 6);
#pragma unroll
            for (int j = 0; j < 4; ++j) {
                orow[j * 16 + l15] = acc[mi][j][rr] * sv + bv;
            }
        }
    }
#undef STAGE
#undef PHASE
}

extern "C" void kernel_launch(void* const* d_in, const int* in_sizes, int n_in,
                              void* d_out, int out_size, void* d_ws, size_t ws_size,
                              hipStream_t stream) {
    const float* x      = (const float*)d_in[0];
    const float* style  = (const float*)d_in[1];
    const float* weight = (const float*)d_in[2];
    const float* bias   = (const float*)d_in[3];
    float* out = (float*)d_out;

    unsigned short* wpk = (unsigned short*)d_ws;                  // 16*9*32*64*8 shorts (4.72 MB)
    unsigned short* xtp = wpk + (size_t)2359296;                  // 8*66*66*512 shorts (35.7 MB)
    float* siginv = (float*)(xtp + (size_t)BB * XPD * XPD * 512); // 8*512 f32

    zring_kernel<<<520, 256, 0, stream>>>(xtp);
    xpose_kernel<<<dim3(16, HH, BB), 256, 0, stream>>>(x, style, xtp);
    wpack_kernel<<<COUT, 256, 0, stream>>>(weight, wpk);
    sigma_kernel<<<COUT, 256, 0, stream>>>(weight, style, siginv);
    conv_kernel<<<1024, 256, 0, stream>>>(wpk, xtp, siginv, bias, out);
}

// Round 9
// 166.974 us; speedup vs baseline: 1.0101x; 1.0101x over previous
//
#include <hip/hip_runtime.h>

#define CIN 512
#define COUT 512
#define HH 64
#define WW 64
#define BB 8
#define KTOT 4608   // 512*9

#define XPD 66                 // padded spatial dim: index = coord+1, coord in -1..64
#define BUFSH (10 * 66 * 32)   // 21120 shorts per buffer (10 rows x 66 slices x 32 ch)
#define BUFB  (BUFSH * 2)      // 42240 bytes per buffer
#define ROWB  (66 * 64)        // 4224 bytes per LDS input row (66 slices x 64 B)

typedef __attribute__((ext_vector_type(8))) short short8;
typedef __attribute__((ext_vector_type(4))) float f32x4;

__device__ inline unsigned short f2bf(float f) {
    unsigned int u = __float_as_uint(f);
    u += 0x7FFFu + ((u >> 16) & 1u);   // round-to-nearest-even
    return (unsigned short)(u >> 16);
}

__device__ inline void gll16(const void* g, void* l) {
    __builtin_amdgcn_global_load_lds(
        (const __attribute__((address_space(1))) unsigned int*)g,
        (__attribute__((address_space(3))) unsigned int*)l, 16, 0, 0);
}

// ---------------- Phase -1: zero the halo ring of XTP ----------------
__global__ __launch_bounds__(256) void zring_kernel(unsigned short* __restrict__ xtp) {
    const int e = blockIdx.x * 256 + threadIdx.x;   // 520*256 >= 8*260*64
    if (e >= BB * 260 * 64) return;
    const int unit = e & 63;
    const int sa = e >> 6;           // 0..2079
    const int b = sa / 260;
    const int s = sa - b * 260;
    int yy, xx;
    if (s < 66)       { yy = 0;        xx = s; }
    else if (s < 132) { yy = 65;       xx = s - 66; }
    else if (s < 196) { yy = s - 131;  xx = 0; }     // rows 1..64
    else              { yy = s - 195;  xx = 65; }    // rows 1..64
    *(short8*)(xtp + ((size_t)(b * XPD + yy) * XPD + xx) * 512 + unit * 8) =
        (short8){0, 0, 0, 0, 0, 0, 0, 0};
}

// ------- Phase 0: x [b][i][y][x] fp32 * (1+style[b][i]) -> XTP [b][y+1][x+1][i] bf16 -------
__global__ __launch_bounds__(256) void xpose_kernel(const float* __restrict__ x,
                                                    const float* __restrict__ style,
                                                    unsigned short* __restrict__ xtp) {
    __shared__ float tile[32 * 65];
    __shared__ float sst[32];
    const int ic = blockIdx.x;   // 16 groups of 32 channels
    const int y  = blockIdx.y;
    const int b  = blockIdx.z;
    const int t  = threadIdx.x;
    if (t < 32) sst[t] = style[b * CIN + ic * 32 + t] + 1.0f;
#pragma unroll
    for (int it = 0; it < 8; ++it) {
        int e = it * 256 + t;
        int ii = e >> 6, xx = e & 63;
        tile[ii * 65 + xx] = x[(((size_t)(b * CIN + ic * 32 + ii) * HH + y) << 6) + xx];
    }
    __syncthreads();
#pragma unroll
    for (int it = 0; it < 8; ++it) {
        int g = it * 256 + t;
        int xx = g >> 5, ii = g & 31;
        xtp[((size_t)(b * XPD + y + 1) * XPD + xx + 1) * 512 + ic * 32 + ii] =
            f2bf(tile[ii * 65 + xx] * sst[ii]);
    }
}

// ---------------- Phase 1a: pack w*c into MFMA fragment layout (batch-independent) -------
// Wpk flat: (((c*9 + tap)*32 + g)*64 + lane)*8 + e ; lane = l4*16+l15 holds
//   W[o = g*16+l15][i = c*32 + l4*8 + e],  c = 16 chunks of 32 input ch.
__global__ __launch_bounds__(256) void wpack_kernel(const float* __restrict__ weight,
                                                    unsigned short* __restrict__ wpk) {
    __shared__ float q[KTOT];
    const int o = blockIdx.x;
    const int t = threadIdx.x;
    const float* wrow = weight + (size_t)o * KTOT;   // e = i*9+tap
    const float cst = 1.0f / sqrtf((float)KTOT);
#pragma unroll
    for (int it = 0; it < 18; ++it) {
        int e = it * 256 + t;
        q[e] = wrow[e] * cst;
    }
    __syncthreads();
    const int g = o >> 4, l15 = o & 15;
    for (int m = t; m < 576; m += 256) {   // m -> (c, tap, l4)
        int c   = m / 36;
        int rem = m - c * 36;
        int tap = rem >> 2;
        int l4  = rem & 3;
        short8 v;
#pragma unroll
        for (int e = 0; e < 8; ++e)
            v[e] = (short)f2bf(q[(c * 32 + l4 * 8 + e) * 9 + tap]);
        *(short8*)(wpk + ((((size_t)c * 9 + tap) * 32 + g) * 64 + l4 * 16 + l15) * 8) = v;
    }
}

// ---------------- Phase 1b: sigma_inv[b][o] = rsqrt(c^2 * sum_i wsq[o,i]*(1+s)^2 + eps) ----
__global__ __launch_bounds__(256) void sigma_kernel(const float* __restrict__ weight,
                                                    const float* __restrict__ style,
                                                    float* __restrict__ siginv) {
    __shared__ float sred[4][8];
    const int o = blockIdx.x;
    const int t = threadIdx.x;
    const float* wrow = weight + (size_t)o * KTOT;
    float acc[8] = {0.f, 0.f, 0.f, 0.f, 0.f, 0.f, 0.f, 0.f};
#pragma unroll
    for (int ii = 0; ii < 2; ++ii) {
        const int i = t * 2 + ii;
        float wsq = 0.f;
#pragma unroll
        for (int tap = 0; tap < 9; ++tap) {
            float v = wrow[i * 9 + tap];
            wsq += v * v;
        }
#pragma unroll
        for (int b = 0; b < 8; ++b) {
            float s = style[b * CIN + i] + 1.0f;
            acc[b] += wsq * s * s;
        }
    }
#pragma unroll
    for (int b = 0; b < 8; ++b) {
        float v = acc[b];
#pragma unroll
        for (int off = 32; off > 0; off >>= 1) v += __shfl_down(v, off, 64);
        if ((t & 63) == 0) sred[t >> 6][b] = v;
    }
    __syncthreads();
    if (t < 8) {
        const float S = sred[0][t] + sred[1][t] + sred[2][t] + sred[3][t];
        siginv[t * COUT + o] = rsqrtf(S * (1.0f / (float)KTOT) + 1e-8f);
    }
}

// ---------------- Phase 2: implicit-GEMM conv ----------------
// block: 512 thr = 8 waves; tile 128 o x 8 output rows x 64 px.
// wave (og = wid&1, rp = wid>>1): 64 o x 2 rows x 64 px -> acc[4][8] (128 AGPR).
// j = 8 -> 128 FLOP per L2-A-byte (the round-8 plateau was the L2 A-stream at
// 64 FLOP/B); rp-waves share identical A-streams -> L1 dedup.
// X: 10 rows x 66 slices x 32 ch per buffer (64B slices, u^((col>>1)&3) swizzle:
// max 2-way = free), double-buffered 84.5 KB -> 1 block/CU, 2 waves/SIMD.
// A: 2-deep static af[3] rotation; 16 ic-chunks x 9 tap-phases; 32 MFMA/phase.
__global__ __launch_bounds__(512, 2) void conv_kernel(const unsigned short* __restrict__ wpk,
                                                      const unsigned short* __restrict__ xtp,
                                                      const float* __restrict__ siginv,
                                                      const float* __restrict__ bias,
                                                      float* __restrict__ out) {
    __shared__ __align__(16) unsigned short xs[2 * BUFSH];   // 84480 B
    // XCD-aware decode: XCD k = bid&7 owns ob = k&3 (1.18 MB weight quarter, L2-hot)
    const int bid = blockIdx.x;             // grid 256 = 1 block/CU
    const int k  = bid & 7;
    const int t  = bid >> 3;                // 0..31
    const int ob = k & 3;
    const int b  = (k >> 2) * 4 + (t >> 3);
    const int rg = t & 7;
    const int y0r = rg * 8;                 // output rows y0r..y0r+7

    const int tid  = threadIdx.x;
    const int lane = tid & 63;
    const int wid_u = __builtin_amdgcn_readfirstlane(tid >> 6);   // wave-uniform -> SGPR
    const int l15 = lane & 15, l4 = lane >> 4;
    const int og = wid_u & 1, rp = wid_u >> 1;   // wave tile: o half, row pair
    const int g0 = ob * 8 + og * 4;              // o-frag base (frags of 16 o), scalar

    // ---- staging precompute: 660 slices (10 rows x 66 cols) of 64 B each.
    // wave-load q covers slices q*16 + (lane>>2); phys unit = lane&3,
    // logical unit = phys ^ ((col>>1)&3)  (inverse swizzle on the global source).
    const int u = lane & 3;
    const unsigned short* srcq[5];
#pragma unroll
    for (int t4 = 0; t4 < 5; ++t4) {
        const int sl = (wid_u + t4 * 8) * 16 + (lane >> 2);
        const int row = sl / 66, col = sl - row * 66;
        srcq[t4] = xtp + ((size_t)(b * XPD + y0r + row) * XPD + col) * 512 +
                   (u ^ ((col >> 1) & 3)) * 8;
    }
    const unsigned short* srcX = xtp;
    if (wid_u <= 1) {   // q = 40 (wid 0, 16 slices) / q = 41 (wid 1, 4 slices, lanes<16)
        const int sl = (40 + wid_u) * 16 + (lane >> 2);
        const int row = sl / 66, col = sl - row * 66;
        const int rowc = (row < 10) ? row : 9;   // lanes>=16 of q41 never load
        srcX = xtp + ((size_t)(b * XPD + y0r + rowc) * XPD + col) * 512 +
               (u ^ ((col >> 1) & 3)) * 8;
    }

    // B ds base addrs (3 regs): col = l15+kx, phys unit = l4 ^ ((col>>1)&3)
    const char* vBp[3];
#pragma unroll
    for (int kx = 0; kx < 3; ++kx)
        vBp[kx] = (const char*)xs + rp * (2 * ROWB) + (l15 + kx) * 64 +
                  ((l4 ^ (((l15 + kx) >> 1) & 3)) * 16);

    f32x4 acc[4][8];
#pragma unroll
    for (int mi = 0; mi < 4; ++mi)
#pragma unroll
        for (int j = 0; j < 8; ++j) acc[mi][j] = (f32x4){0.f, 0.f, 0.f, 0.f};

    short8 af[3][4];   // 2-deep prefetch rotation; slot = tap % 3 (9 % 3 == 0: seamless)

    // A frag addr (shorts): aP + (ic*9+tap)*16384 + mi*512
    const unsigned short* aP = wpk + (size_t)g0 * 512 + lane * 8;

#define STAGE(bufp, icq)                                                                  \
    do {                                                                                  \
        unsigned short* db = xs + (bufp) * BUFSH;                                         \
        _Pragma("unroll") for (int t4 = 0; t4 < 5; ++t4)                                  \
            gll16(srcq[t4] + (size_t)(icq) * 32, db + (wid_u + t4 * 8) * 512);            \
        if (wid_u == 0)                                                                   \
            gll16(srcX + (size_t)(icq) * 32, db + 40 * 512);                              \
        else if (wid_u == 1 && lane < 16)                                                 \
            gll16(srcX + (size_t)(icq) * 32, db + 41 * 512);                              \
    } while (0)

#define TAPPHASE(tp, P, aIC)                                                              \
    do {                                                                                  \
        const unsigned short* pA = (aIC) + (size_t)((tp) + 2) * 16384;                    \
        _Pragma("unroll") for (int mi = 0; mi < 4; ++mi)                                  \
            af[((tp) + 2) % 3][mi] = *(const short8*)(pA + mi * 512);                     \
        short8 bfr[8];                                                                    \
        _Pragma("unroll") for (int j = 0; j < 8; ++j)                                     \
            bfr[j] = *(const short8*)(vBp[(tp) % 3] + (P) * BUFB +                        \
                ((tp) / 3 + (j >> 2)) * ROWB + (j & 3) * 1024);                           \
        __builtin_amdgcn_s_setprio(1);                                                    \
        _Pragma("unroll") for (int mi = 0; mi < 4; ++mi)                                  \
            _Pragma("unroll") for (int j = 0; j < 8; ++j)                                 \
                acc[mi][j] = __builtin_amdgcn_mfma_f32_16x16x32_bf16(                     \
                    af[(tp) % 3][mi], bfr[j], acc[mi][j], 0, 0, 0);                       \
        __builtin_amdgcn_s_setprio(0);                                                    \
    } while (0)

#define ICBODY(icv, P)                                                                    \
    do {                                                                                  \
        if ((icv) < 15) STAGE((P) ^ 1, (icv) + 1);                                        \
        const unsigned short* aIC = aP + (size_t)(icv) * (9 * 16384);                     \
        TAPPHASE(0, P, aIC); TAPPHASE(1, P, aIC); TAPPHASE(2, P, aIC);                    \
        TAPPHASE(3, P, aIC); TAPPHASE(4, P, aIC); TAPPHASE(5, P, aIC);                    \
        TAPPHASE(6, P, aIC); TAPPHASE(7, P, aIC); TAPPHASE(8, P, aIC);                    \
        __syncthreads();                                                                  \
    } while (0)

    // prologue: A slots 0 (G=0) and 1 (G=1), stage buffer 0
#pragma unroll
    for (int mi = 0; mi < 4; ++mi) af[0][mi] = *(const short8*)(aP + mi * 512);
#pragma unroll
    for (int mi = 0; mi < 4; ++mi) af[1][mi] = *(const short8*)(aP + 16384 + mi * 512);
    STAGE(0, 0);
    __syncthreads();

#pragma unroll 1
    for (int ic = 0; ic < 16; ic += 2) {
        ICBODY(ic, 0);
        ICBODY(ic + 1, 1);
    }

    // epilogue: D-frag col = l15 (px), row = l4*4 + rr (o); scale by sigma_inv, add bias
    const int yb0 = y0r + rp * 2;
#pragma unroll
    for (int mi = 0; mi < 4; ++mi) {
        const int obase = ob * 128 + og * 64 + mi * 16 + l4 * 4;
#pragma unroll
        for (int rr = 0; rr < 4; ++rr) {
            const int o = obase + rr;
            const float sv = siginv[b * COUT + o];
            const float bv = bias[o];
#pragma unroll
            for (int j = 0; j < 8; ++j) {
                const int yout = yb0 + (j >> 2);
                out[(((size_t)(b * COUT + o) * HH + yout) << 6) + (j & 3) * 16 + l15] =
                    acc[mi][j][rr] * sv + bv;
            }
        }
    }
#undef STAGE
#undef TAPPHASE
#undef ICBODY
}

extern "C" void kernel_launch(void* const* d_in, const int* in_sizes, int n_in,
                              void* d_out, int out_size, void* d_ws, size_t ws_size,
                              hipStream_t stream) {
    const float* x      = (const float*)d_in[0];
    const float* style  = (const float*)d_in[1];
    const float* weight = (const float*)d_in[2];
    const float* bias   = (const float*)d_in[3];
    float* out = (float*)d_out;

    unsigned short* wpk = (unsigned short*)d_ws;                  // 16*9*32*64*8 shorts (4.72 MB)
    unsigned short* xtp = wpk + (size_t)2359296;                  // 8*66*66*512 shorts (35.7 MB)
    float* siginv = (float*)(xtp + (size_t)BB * XPD * XPD * 512); // 8*512 f32

    zring_kernel<<<520, 256, 0, stream>>>(xtp);
    xpose_kernel<<<dim3(16, HH, BB), 256, 0, stream>>>(x, style, xtp);
    wpack_kernel<<<COUT, 256, 0, stream>>>(weight, wpk);
    sigma_kernel<<<COUT, 256, 0, stream>>>(weight, style, siginv);
    conv_kernel<<<256, 512, 0, stream>>>(wpk, xtp, siginv, bias, out);
}